// Round 16
// baseline (118.485 us; speedup 1.0000x reference)
//
#include <hip/hip_runtime.h>
#include <hip/hip_bf16.h>

// Problem constants
#define N_PAIRS   64000
#define N_ATOMS   16000
#define N_FEAT    8
#define N_HIDDEN  100
// Aggregate-first, scatter-forward dataflow (no divergent reads on hot path):
//   hist:  bucket edges by dest (pack (e<<14)|src); write pf[e] into pfe at
//          the dest-slot; record eaf slot (d*8+slot) in a src-bucket.
//   stage: one wave per src: read af row once (coalesced), bf16-convert,
//          scatter-write to its out-edges' eaf slots (fire-and-forget).
//   fused: per dest read 8 eaf rows (coalesced) + pfe (contiguous scalar),
//          FMA -> S row in LDS -> MFMA GEMM with Wbig^T -> out.
#define SW        1024    // wtb2 row stride (stored transposed: wtb2[i][k])
#define SKL       936     // LDS S-tile row stride (bf16)
#define BD        32      // bucket_dest stride (cap 32; P(deg>32|Poisson4)~1e-18)
#define BS        24      // bsrc stride (P(degout>24)~1e-11/atom)
#define EST       128     // eaf slot stride (ushort), 256 B aligned

#define SETUP_BLOCKS (112 * 1024 / 256)    // 448
#define HIST_BLOCKS  (N_PAIRS / 256)       // 250

typedef __attribute__((ext_vector_type(8))) short bf16x8_t;   // 8 bf16 = 4 VGPRs
typedef __attribute__((ext_vector_type(4))) float f32x4_t;

// ---- setup_hist: [0,448) wtb2[i][k] = Wbig[k][i] (bf16, padded);
//      [448,698) edge histogram: dest-bucket + pfe scatter + src-bucket.
__global__ __launch_bounds__(256) void setup_hist(const float* __restrict__ W,
                                                  const float* __restrict__ b,
                                                  const int* __restrict__ a2p,
                                                  const float* __restrict__ pf,
                                                  __hip_bfloat16* __restrict__ wtb2,
                                                  int* __restrict__ deg_d,
                                                  int* __restrict__ deg_s,
                                                  unsigned* __restrict__ bucket_dest,
                                                  unsigned* __restrict__ bsrc,
                                                  float* __restrict__ pfe) {
    int bid = blockIdx.x;
    if (bid < SETUP_BLOCKS) {
        int id = bid * 256 + threadIdx.x;          // < 114688
        int i = id >> 10;                          // 0..111 (output col)
        int k = id & 1023;                         // 0..1023 (contraction index)
        float v = 0.f;
        if (i < N_HIDDEN) {
            if (k < 800) {
                int f = k / N_HIDDEN;
                int j = k - f * N_HIDDEN;
                v = W[f * (N_HIDDEN * N_HIDDEN) + i * N_HIDDEN + j];
            } else if (k < 900) {
                int j = k - 800;
                v = b[i * N_HIDDEN + j];
            }
        }
        wtb2[id] = __float2bfloat16(v);
    } else {
        int e = (bid - SETUP_BLOCKS) * 256 + threadIdx.x;   // < 64000 exactly
        int d = a2p[e * 2];
        int s = a2p[e * 2 + 1];
        int slot_d = atomicAdd(&deg_d[d], 1);
        if (slot_d < BD)
            bucket_dest[d * BD + slot_d] = ((unsigned)e << 14) | (unsigned)s;
        unsigned val = 0xFFFFFFFFu;                // sentinel: not staged
        if (slot_d < 8) {
            val = (unsigned)(d * 8 + slot_d);
            const float4* ps = (const float4*)(pf + e * N_FEAT);
            float4* pd = (float4*)(pfe + (size_t)(d * 8 + slot_d) * N_FEAT);
            pd[0] = ps[0];
            pd[1] = ps[1];
        }
        int slot_s = atomicAdd(&deg_s[s], 1);
        if (slot_s < BS)
            bsrc[s * BS + slot_s] = val;
    }
}

// ---- stage: one wave per src atom. Read af row once (coalesced fp32),
//      truncate to bf16, scatter-write to each out-edge's eaf slot.
//      Fire-and-forget: no dependent consumer, pure write throughput.
__global__ __launch_bounds__(256) void stage_kernel(const float* __restrict__ af,
                                                    const int* __restrict__ deg_s,
                                                    const unsigned* __restrict__ bsrc,
                                                    unsigned short* __restrict__ eaf) {
    int wave = threadIdx.x >> 6;
    int lane = threadIdx.x & 63;
    int s = __builtin_amdgcn_readfirstlane(blockIdx.x * 4 + wave);  // src atom
    int ds = deg_s[s];                             // scalar load
    if (ds > BS) ds = BS;
    bool act = (lane < 50);

    unsigned u = 0;
    if (act) {
        float2 v = *(const float2*)(af + s * N_HIDDEN + 2 * lane);  // coalesced
        u = (__float_as_uint(v.y) & 0xFFFF0000u) | (__float_as_uint(v.x) >> 16);
    }
    const unsigned* sb = bsrc + s * BS;            // SGPR base, contiguous
    for (int t = 0; t < ds; ++t) {
        unsigned slot = sb[t];                     // scalar load
        if (slot != 0xFFFFFFFFu && act)
            *(unsigned*)(eaf + (size_t)slot * EST + 2 * lane) = u;  // 200 B/row
    }
}

// ---- fused: one block = 16 dest atoms, 512 threads (8 waves), 30 KB LDS.
//      Phase 1: wave w owns tile rows 2w, 2w+1. Per dest: 8 coalesced eaf
//      row loads (predicated by ns) + pfe contiguous scalar loads (address
//      depends only on d) -> FMA with SGPR pf operands. Serial depth 2.
//      Rare deg>8 remainder gathers af fp32 directly (bucket_dest metadata).
//      Phase 2: waves 0..6 each do one 16-col n-tile of S_tile @ wtb2^T.
__global__ __launch_bounds__(512) void fused_edge_gemm(const float* __restrict__ af,
                                                       const float* __restrict__ pf,
                                                       const int* __restrict__ deg_d,
                                                       const unsigned* __restrict__ bucket_dest,
                                                       const float* __restrict__ pfe,
                                                       const unsigned short* __restrict__ eaf,
                                                       const __hip_bfloat16* __restrict__ wtb2,
                                                       float* __restrict__ out) {
    __shared__ __hip_bfloat16 St[16 * SKL];            // 29,952 B
    int blk  = blockIdx.x;                             // 0..999
    int wave = threadIdx.x >> 6;
    int lane = threadIdx.x & 63;
    bool act = (lane < 50);                            // cols 2*lane, 2*lane+1

#pragma unroll
    for (int j = 0; j < 2; ++j) {
        int r = wave * 2 + j;                          // tile row 0..15
        int d = __builtin_amdgcn_readfirstlane(blk * 16 + r);   // force SGPR
        int n = deg_d[d];                              // scalar load
        if (n > BD) n = BD;
        int ns = n < 8 ? n : 8;

        // 8 independent COALESCED eaf row loads (only dep: ns)
        const unsigned short* ebase = eaf + (size_t)d * 8 * EST;
        unsigned uu[8];
#pragma unroll
        for (int t = 0; t < 8; ++t)
            uu[t] = (t < ns && act) ? *(const unsigned*)(ebase + t * EST + 2 * lane) : 0u;

        // pf block: contiguous scalar loads, address depends only on d
        const float* pp = pfe + (size_t)d * 64;        // 64 floats -> wide s_loads

        float acc[9][2] = {};                          // f=0..7 weighted, f=8 bias
#pragma unroll
        for (int t = 0; t < 8; ++t) {
            float ax = __uint_as_float(uu[t] << 16);
            float ay = __uint_as_float(uu[t] & 0xFFFF0000u);
#pragma unroll
            for (int f = 0; f < N_FEAT; ++f) {
                float p = pp[t * 8 + f];               // SGPR; poison beyond ns is
                acc[f][0] += p * ax;                   // finite (0xAA..) and a=0
                acc[f][1] += p * ay;
            }
            acc[8][0] += ax;
            acc[8][1] += ay;
        }
        // rare remainder (deg>8): direct fp32 gather via bucket_dest
        const unsigned* sbd = bucket_dest + (size_t)d * BD;
        for (int t0 = 8; t0 < n; t0 += 4) {
            unsigned pk[4];
#pragma unroll
            for (int u = 0; u < 4; ++u)
                pk[u] = sbd[(t0 + u) < n ? (t0 + u) : 0];
            float2 a[4];
#pragma unroll
            for (int u = 0; u < 4; ++u) {
                int src = (int)(pk[u] & 16383u);
                a[u] = ((t0 + u) < n && act)
                     ? *(const float2*)(af + src * N_HIDDEN + 2 * lane)
                     : make_float2(0.f, 0.f);
            }
#pragma unroll
            for (int u = 0; u < 4; ++u) {
                int e = (int)(pk[u] >> 14);
                const float* pe = pf + e * N_FEAT;     // scalar
#pragma unroll
                for (int f = 0; f < N_FEAT; ++f) {
                    float p = pe[f];
                    acc[f][0] += p * a[u].x;
                    acc[f][1] += p * a[u].y;
                }
                acc[8][0] += a[u].x;
                acc[8][1] += a[u].y;
            }
        }

        // write S row to LDS (bf16); lanes 50..63 zero the K-pad cols 900..927
        __hip_bfloat16* srow = St + r * SKL;
        if (act) {
#pragma unroll
            for (int f = 0; f < 9; ++f) {
                __hip_bfloat162 h;
                h.x = __float2bfloat16(acc[f][0]);
                h.y = __float2bfloat16(acc[f][1]);
                *(__hip_bfloat162*)(srow + f * N_HIDDEN + 2 * lane) = h;
            }
        } else {
            __hip_bfloat162 z;
            z.x = __float2bfloat16(0.f);
            z.y = z.x;
            *(__hip_bfloat162*)(srow + 900 + 2 * (lane - 50)) = z;   // 900..927
        }
    }
    __syncthreads();

    // ---- phase 2: out[16 rows] = S_tile @ wtb2^T; wave w -> n-tile w (w<7)
    if (wave < 7) {
        int quad = lane >> 4;
        int l15  = lane & 15;
        int m0   = blk * 16;
        const __hip_bfloat16* as = St + l15 * SKL + quad * 8;
        const __hip_bfloat16* bp = wtb2 + (size_t)(wave * 16 + l15) * SW + quad * 8;
        f32x4_t accd = {0.f, 0.f, 0.f, 0.f};
#pragma unroll
        for (int k = 0; k < 29; ++k) {
            bf16x8_t aa = *(const bf16x8_t*)(as + k * 32);
            bf16x8_t bb = *(const bf16x8_t*)(bp + k * 32);
            accd = __builtin_amdgcn_mfma_f32_16x16x32_bf16(aa, bb, accd, 0, 0, 0);
        }
        int c = wave * 16 + l15;
        if (c < N_HIDDEN) {                            // wave 6 covers cols 96..99
#pragma unroll
            for (int rr = 0; rr < 4; ++rr)
                out[(size_t)(m0 + quad * 4 + rr) * N_HIDDEN + c] = accd[rr];
        }
    }
}

extern "C" void kernel_launch(void* const* d_in, const int* in_sizes, int n_in,
                              void* d_out, int out_size, void* d_ws, size_t ws_size,
                              hipStream_t stream) {
    const float* pf  = (const float*)d_in[0];   // (64000, 8)
    const float* af  = (const float*)d_in[1];   // (16000, 100)
    const int*   a2p = (const int*)d_in[2];     // (64000, 2)
    const float* W   = (const float*)d_in[3];   // (8, 10000)
    const float* b   = (const float*)d_in[4];   // (10000,)
    float* out = (float*)d_out;                 // (16000, 100) fp32

    char* ws = (char*)d_ws;
    __hip_bfloat16* wtb2     = (__hip_bfloat16*)ws;               //   229,376 B
    int* deg_d               = (int*)(ws + 229376);               //    64,000 B
    int* deg_s               = (int*)(ws + 293376);               //    64,000 B
    unsigned* bucket_dest    = (unsigned*)(ws + 357376);          // 2,048,000 B
    unsigned* bsrc           = (unsigned*)(ws + 2405376);         // 1,536,000 B
    float* pfe               = (float*)(ws + 3941376);            // 4,096,000 B
    unsigned short* eaf      = (unsigned short*)(ws + 8037376);   // 32,768,000 B (end ~40.8 MB)

    hipMemsetAsync(ws + 229376, 0, 128000, stream);   // deg_d + deg_s
    setup_hist<<<SETUP_BLOCKS + HIST_BLOCKS, 256, 0, stream>>>(
        W, b, a2p, pf, wtb2, deg_d, deg_s, bucket_dest, bsrc, pfe);
    stage_kernel<<<N_ATOMS / 4, 256, 0, stream>>>(af, deg_s, bsrc, eaf);
    fused_edge_gemm<<<N_ATOMS / 16, 512, 0, stream>>>(
        af, pf, deg_d, bucket_dest, pfe, eaf, wtb2, out);
}